// Round 1
// baseline (262.070 us; speedup 1.0000x reference)
//
#include <hip/hip_runtime.h>

typedef __attribute__((ext_vector_type(8))) short bf16x8;
typedef __attribute__((ext_vector_type(4))) float f32x4;

#define NTOK 2048
#define DDIM 1024
#define HDIM 4096
#define KEXP 8

#define BM 256
#define BN 64
#define BK 64
#define LDSS 72  // LDS row stride in bf16 elems (144B: 16B-aligned, 2-way banks)

__device__ __forceinline__ unsigned short f2bf(float f) {
  union { float f; unsigned int u; } c; c.f = f;
  unsigned int u = c.u;
  return (unsigned short)((u + 0x7FFFu + ((u >> 16) & 1u)) >> 16);  // RNE
}

// ---------------- routing: counting sort of tokens by expert ----------------
__global__ void route_kernel(const float* __restrict__ cw, int* __restrict__ offs,
                             int* __restrict__ perm, float* __restrict__ wsel) {
  __shared__ int cnt[KEXP];
  __shared__ int base[KEXP];
  const int t = threadIdx.x;  // 256 threads, 8 tokens each
  if (t < KEXP) cnt[t] = 0;
  __syncthreads();
  int eid[8]; float wv[8];
  #pragma unroll
  for (int i = 0; i < 8; i++) {
    const int tok = t * 8 + i;
    const float* p = cw + tok * KEXP;
    int best = 0; float bw = p[0];
    #pragma unroll
    for (int k = 1; k < KEXP; k++) { float v = p[k]; if (v > bw) { bw = v; best = k; } }
    eid[i] = best; wv[i] = bw;
    atomicAdd(&cnt[best], 1);
  }
  __syncthreads();
  if (t == 0) {
    int s = 0;
    for (int k = 0; k < KEXP; k++) { base[k] = s; offs[k] = s; s += cnt[k]; }
    offs[KEXP] = s;
  }
  __syncthreads();
  #pragma unroll
  for (int i = 0; i < 8; i++) {
    const int tok = t * 8 + i;
    const int pos = atomicAdd(&base[eid[i]], 1);
    perm[pos] = tok;
    wsel[pos] = wv[i];
  }
}

// ---------------- gather x rows into expert-sorted bf16 ----------------
__global__ void gather_x(const float* __restrict__ x, const int* __restrict__ perm,
                         unsigned short* __restrict__ Xb) {
  const int slot = blockIdx.x;
  const int tok = perm[slot];
  const int t = threadIdx.x;  // 256
  float4 v = ((const float4*)(x + (size_t)tok * DDIM))[t];
  ushort4 o; o.x = f2bf(v.x); o.y = f2bf(v.y); o.z = f2bf(v.z); o.w = f2bf(v.w);
  ((ushort4*)(Xb + (size_t)slot * DDIM))[t] = o;
}

// ---------------- pass 1: H = silu(X@wg) * (X@wu), grouped by expert ----------------
__global__ __launch_bounds__(512) void gemm_swiglu(
    const unsigned short* __restrict__ Xb,
    const float* __restrict__ wg, const float* __restrict__ wu,
    const int* __restrict__ offs, unsigned short* __restrict__ Hb) {
  __shared__ unsigned short As[BM * LDSS];
  __shared__ unsigned short Bg[BN * LDSS];
  __shared__ unsigned short Bu[BN * LDSS];

  const int e = blockIdx.y;
  const int s0 = offs[e], s1 = offs[e + 1];
  const int slot0 = s0 + blockIdx.z * BM;
  if (slot0 >= s1) return;
  const int Msub = s1 - slot0;
  const int n0 = blockIdx.x * BN;

  const float* Wg = wg + (size_t)e * DDIM * HDIM;
  const float* Wu = wu + (size_t)e * DDIM * HDIM;

  const int t = threadIdx.x;
  const int lane = t & 63;
  const int wid = t >> 6;
  const int wm = wid >> 1;  // 0..3 -> 64-row strip
  const int wn = wid & 1;   // 0..1 -> 32-col strip
  const int l15 = lane & 15;
  const int lhi = lane >> 4;

  // A staging: thread -> (row = t>>1, koff = (t&1)*32), 4x 16B
  const int a_row = t >> 1;
  const int a_koff = (t & 1) * 32;
  const unsigned short* a_src = Xb + (size_t)min(slot0 + a_row, NTOK - 1) * DDIM + a_koff;
  unsigned short* a_dst = As + a_row * LDSS + a_koff;

  // B staging: thread -> (n4 = (t&15)*4, kk = (t>>4)*2), 2x float4 per matrix
  const int b_n4 = (t & 15) * 4;
  const int b_kk = (t >> 4) * 2;

  f32x4 accg[4][2] = {};
  f32x4 accu[4][2] = {};

  for (int k0 = 0; k0 < DDIM; k0 += BK) {
    {  // stage A (bf16, linear copy)
      const uint4* s = (const uint4*)(a_src + k0);
      uint4* d = (uint4*)a_dst;
      #pragma unroll
      for (int j = 0; j < 4; j++) d[j] = s[j];
    }
    {  // stage B: f32 load, cvt bf16, transposed [n][k] store
      const float* pg = Wg + (size_t)(k0 + b_kk) * HDIM + n0 + b_n4;
      const float* pu = Wu + (size_t)(k0 + b_kk) * HDIM + n0 + b_n4;
      float4 g0 = *(const float4*)pg;
      float4 g1 = *(const float4*)(pg + HDIM);
      float4 u0 = *(const float4*)pu;
      float4 u1 = *(const float4*)(pu + HDIM);
      #pragma unroll
      for (int c = 0; c < 4; c++) {
        *(unsigned int*)(Bg + (b_n4 + c) * LDSS + b_kk) =
            (unsigned)f2bf(((const float*)&g0)[c]) | ((unsigned)f2bf(((const float*)&g1)[c]) << 16);
        *(unsigned int*)(Bu + (b_n4 + c) * LDSS + b_kk) =
            (unsigned)f2bf(((const float*)&u0)[c]) | ((unsigned)f2bf(((const float*)&u1)[c]) << 16);
      }
    }
    __syncthreads();
    #pragma unroll
    for (int ks = 0; ks < 2; ks++) {
      const int kof = ks * 32 + lhi * 8;
      bf16x8 af[4];
      #pragma unroll
      for (int fm = 0; fm < 4; fm++)
        af[fm] = *(const bf16x8*)(As + (wm * 64 + fm * 16 + l15) * LDSS + kof);
      #pragma unroll
      for (int fn = 0; fn < 2; fn++) {
        bf16x8 bgf = *(const bf16x8*)(Bg + (wn * 32 + fn * 16 + l15) * LDSS + kof);
        bf16x8 buf = *(const bf16x8*)(Bu + (wn * 32 + fn * 16 + l15) * LDSS + kof);
        #pragma unroll
        for (int fm = 0; fm < 4; fm++) {
          accg[fm][fn] = __builtin_amdgcn_mfma_f32_16x16x32_bf16(af[fm], bgf, accg[fm][fn], 0, 0, 0);
          accu[fm][fn] = __builtin_amdgcn_mfma_f32_16x16x32_bf16(af[fm], buf, accu[fm][fn], 0, 0, 0);
        }
      }
    }
    __syncthreads();
  }

  // epilogue: silu(g)*u -> bf16 Hb  (C/D map: row=(lane>>4)*4+i, col=lane&15)
  #pragma unroll
  for (int fm = 0; fm < 4; fm++) {
    #pragma unroll
    for (int i = 0; i < 4; i++) {
      const int row = wm * 64 + fm * 16 + lhi * 4 + i;
      if (row < Msub) {
        const size_t base = (size_t)(slot0 + row) * HDIM + n0;
        #pragma unroll
        for (int fn = 0; fn < 2; fn++) {
          const float g = accg[fm][fn][i];
          const float u = accu[fm][fn][i];
          const float h = (g / (1.0f + __expf(-g))) * u;
          Hb[base + wn * 32 + fn * 16 + l15] = f2bf(h);
        }
      }
    }
  }
}

// ---------------- pass 2: Y = H @ wd, scatter to token order ----------------
__global__ __launch_bounds__(512) void gemm_down(
    const unsigned short* __restrict__ Hb, const float* __restrict__ wd,
    const int* __restrict__ offs, const int* __restrict__ perm,
    const float* __restrict__ wsel, float* __restrict__ y) {
  __shared__ unsigned short As[BM * LDSS];
  __shared__ unsigned short Bs[BN * LDSS];

  const int e = blockIdx.y;
  const int s0 = offs[e], s1 = offs[e + 1];
  const int slot0 = s0 + blockIdx.z * BM;
  if (slot0 >= s1) return;
  const int Msub = s1 - slot0;
  const int n0 = blockIdx.x * BN;

  const float* Wd = wd + (size_t)e * HDIM * DDIM;

  const int t = threadIdx.x;
  const int lane = t & 63;
  const int wid = t >> 6;
  const int wm = wid >> 1;
  const int wn = wid & 1;
  const int l15 = lane & 15;
  const int lhi = lane >> 4;

  const int a_row = t >> 1;
  const int a_koff = (t & 1) * 32;
  const unsigned short* a_src = Hb + (size_t)min(slot0 + a_row, NTOK - 1) * HDIM + a_koff;
  unsigned short* a_dst = As + a_row * LDSS + a_koff;

  const int b_n4 = (t & 15) * 4;
  const int b_kk = (t >> 4) * 2;

  f32x4 acc[4][2] = {};

  for (int k0 = 0; k0 < HDIM; k0 += BK) {
    {
      const uint4* s = (const uint4*)(a_src + k0);
      uint4* d = (uint4*)a_dst;
      #pragma unroll
      for (int j = 0; j < 4; j++) d[j] = s[j];
    }
    {
      const float* pw = Wd + (size_t)(k0 + b_kk) * DDIM + n0 + b_n4;
      float4 w0 = *(const float4*)pw;
      float4 w1 = *(const float4*)(pw + DDIM);
      #pragma unroll
      for (int c = 0; c < 4; c++) {
        *(unsigned int*)(Bs + (b_n4 + c) * LDSS + b_kk) =
            (unsigned)f2bf(((const float*)&w0)[c]) | ((unsigned)f2bf(((const float*)&w1)[c]) << 16);
      }
    }
    __syncthreads();
    #pragma unroll
    for (int ks = 0; ks < 2; ks++) {
      const int kof = ks * 32 + lhi * 8;
      bf16x8 af[4];
      #pragma unroll
      for (int fm = 0; fm < 4; fm++)
        af[fm] = *(const bf16x8*)(As + (wm * 64 + fm * 16 + l15) * LDSS + kof);
      #pragma unroll
      for (int fn = 0; fn < 2; fn++) {
        bf16x8 bf = *(const bf16x8*)(Bs + (wn * 32 + fn * 16 + l15) * LDSS + kof);
        #pragma unroll
        for (int fm = 0; fm < 4; fm++)
          acc[fm][fn] = __builtin_amdgcn_mfma_f32_16x16x32_bf16(af[fm], bf, acc[fm][fn], 0, 0, 0);
      }
    }
    __syncthreads();
  }

  #pragma unroll
  for (int fm = 0; fm < 4; fm++) {
    #pragma unroll
    for (int i = 0; i < 4; i++) {
      const int row = wm * 64 + fm * 16 + lhi * 4 + i;
      if (row < Msub) {
        const int slot = slot0 + row;
        const int tok = perm[slot];
        const float w = wsel[slot];
        const size_t base = (size_t)tok * DDIM + n0;
        #pragma unroll
        for (int fn = 0; fn < 2; fn++)
          y[base + wn * 32 + fn * 16 + l15] = acc[fm][fn][i] * w;
      }
    }
  }
}

extern "C" void kernel_launch(void* const* d_in, const int* in_sizes, int n_in,
                              void* d_out, int out_size, void* d_ws, size_t ws_size,
                              hipStream_t stream) {
  const float* x  = (const float*)d_in[0];
  const float* cw = (const float*)d_in[1];
  const float* wg = (const float*)d_in[2];
  const float* wu = (const float*)d_in[3];
  const float* wd = (const float*)d_in[4];
  float* y = (float*)d_out;

  char* ws = (char*)d_ws;
  int* offs   = (int*)ws;                         // 16 ints
  int* perm   = (int*)(ws + 64);                  // 2048 ints
  float* wsel = (float*)(ws + 64 + NTOK * 4);     // 2048 floats
  unsigned short* Xb = (unsigned short*)(ws + 32768);                    // 4 MB
  unsigned short* Hb = (unsigned short*)(ws + 32768 + (size_t)NTOK * DDIM * 2);  // 16 MB

  route_kernel<<<1, 256, 0, stream>>>(cw, offs, perm, wsel);
  gather_x<<<NTOK, 256, 0, stream>>>(x, perm, Xb);
  gemm_swiglu<<<dim3(HDIM / BN, KEXP, 2), 512, 0, stream>>>(Xb, wg, wu, offs, Hb);
  gemm_down<<<dim3(DDIM / BN, KEXP, 2), 512, 0, stream>>>(Hb, wd, offs, perm, wsel, y);
}

// Round 2
// 241.245 us; speedup vs baseline: 1.0863x; 1.0863x over previous
//
#include <hip/hip_runtime.h>

typedef __attribute__((ext_vector_type(8))) short bf16x8;
typedef __attribute__((ext_vector_type(4))) float f32x4;
typedef unsigned short u16;

#define NTOK 2048
#define DDIM 1024
#define HDIM 4096
#define KEXP 8

#define BM 256
#define BK 64
#define LDSS 72  // LDS row stride in bf16 elems (144B): b128 reads/writes bank-balanced

__device__ __forceinline__ u16 f2bf(float f) {
  union { float f; unsigned int u; } c; c.f = f;
  unsigned int u = c.u;
  return (u16)((u + 0x7FFFu + ((u >> 16) & 1u)) >> 16);  // RNE
}

// ---------------- routing: counting sort of tokens by expert ----------------
__global__ void route_kernel(const float* __restrict__ cw, int* __restrict__ offs,
                             int* __restrict__ perm, float* __restrict__ wsel) {
  __shared__ int cnt[KEXP];
  __shared__ int base[KEXP];
  const int t = threadIdx.x;  // 256 threads, 8 tokens each
  if (t < KEXP) cnt[t] = 0;
  __syncthreads();
  int eid[8]; float wv[8];
  #pragma unroll
  for (int i = 0; i < 8; i++) {
    const int tok = t * 8 + i;
    const float* p = cw + tok * KEXP;
    int best = 0; float bw = p[0];
    #pragma unroll
    for (int k = 1; k < KEXP; k++) { float v = p[k]; if (v > bw) { bw = v; best = k; } }
    eid[i] = best; wv[i] = bw;
    atomicAdd(&cnt[best], 1);
  }
  __syncthreads();
  if (t == 0) {
    int s = 0;
    for (int k = 0; k < KEXP; k++) { base[k] = s; offs[k] = s; s += cnt[k]; }
    offs[KEXP] = s;
  }
  __syncthreads();
  #pragma unroll
  for (int i = 0; i < 8; i++) {
    const int tok = t * 8 + i;
    const int pos = atomicAdd(&base[eid[i]], 1);
    perm[pos] = tok;
    wsel[pos] = wv[i];
  }
}

// ---------------- gather x rows into expert-sorted bf16 ----------------
__global__ void gather_x(const float* __restrict__ x, const int* __restrict__ perm,
                         u16* __restrict__ Xb) {
  const int slot = blockIdx.x;
  const int tok = perm[slot];
  const int t = threadIdx.x;  // 256
  float4 v = ((const float4*)(x + (size_t)tok * DDIM))[t];
  ushort4 o; o.x = f2bf(v.x); o.y = f2bf(v.y); o.z = f2bf(v.z); o.w = f2bf(v.w);
  ((ushort4*)(Xb + (size_t)slot * DDIM))[t] = o;
}

// ---------------- pass 1: H = silu(X@wg) * (X@wu) ----------------
// 1024 thr = 16 waves (4m x 4n), BM=256, BN=64, BK=64. Reg-prefetch pipeline.
__global__ __launch_bounds__(1024, 4) void gemm_swiglu(
    const u16* __restrict__ Xb,
    const float* __restrict__ wg, const float* __restrict__ wu,
    const int* __restrict__ offs, u16* __restrict__ Hb) {
  __shared__ u16 As[BM * LDSS];
  __shared__ u16 Bg[64 * LDSS];
  __shared__ u16 Bu[64 * LDSS];

  const int e = blockIdx.y;
  const int s0 = offs[e], s1 = offs[e + 1];
  const int slot0 = s0 + blockIdx.z * BM;
  if (slot0 >= s1) return;
  const int Msub = s1 - slot0;
  const int n0 = blockIdx.x * 64;

  const int t = threadIdx.x;
  const int lane = t & 63;
  const int W = t >> 6;      // wave 0..15
  const int wm = W >> 2;     // 4 m-strips of 64 rows
  const int wn = W & 3;      // 4 n-strips of 16 cols
  const int l15 = lane & 15;
  const int lhi = lane >> 4;

  // A staging: thread -> row t>>2, 32 contiguous bytes at elem (t&3)*16
  const int a_row = t >> 2;
  const int a_ck = (t & 3) * 16;
  const u16* a_src = Xb + (size_t)min(slot0 + a_row, NTOK - 1) * DDIM + a_ck;
  u16* a_dst = As + a_row * LDSS + a_ck;

  // B staging: threads <512 stage Bg, >=512 stage Bu.
  // thread -> n-row (t&63), k-chunk (t>>6)&7: 8 coalesced scalar f32 loads, one b128 write.
  const float* Wsrc = ((t < 512) ? wg : wu) + (size_t)e * DDIM * HDIM;
  const int b_n = t & 63;
  const int b_c8 = (t >> 6) & 7;
  const float* b_src = Wsrc + (size_t)(b_c8 * 8) * HDIM + n0 + b_n;
  u16* b_dst = ((t < 512) ? Bg : Bu) + b_n * LDSS + b_c8 * 8;

  uint4 a0, a1;
  float br[8];

  f32x4 accg[4] = {{0.f,0.f,0.f,0.f},{0.f,0.f,0.f,0.f},{0.f,0.f,0.f,0.f},{0.f,0.f,0.f,0.f}};
  f32x4 accu[4] = {{0.f,0.f,0.f,0.f},{0.f,0.f,0.f,0.f},{0.f,0.f,0.f,0.f},{0.f,0.f,0.f,0.f}};

  // prologue loads for tile 0
  {
    const uint4* s = (const uint4*)(a_src + 0);
    a0 = s[0]; a1 = s[1];
    #pragma unroll
    for (int i = 0; i < 8; i++) br[i] = b_src[(size_t)i * HDIM];
  }

  for (int it = 0; it < DDIM / BK; ++it) {
    if (it > 0) __syncthreads();   // B/A readers of prev tile done
    // write current tile regs -> LDS
    ((uint4*)a_dst)[0] = a0;
    ((uint4*)a_dst)[1] = a1;
    {
      unsigned int pk0 = (unsigned)f2bf(br[0]) | ((unsigned)f2bf(br[1]) << 16);
      unsigned int pk1 = (unsigned)f2bf(br[2]) | ((unsigned)f2bf(br[3]) << 16);
      unsigned int pk2 = (unsigned)f2bf(br[4]) | ((unsigned)f2bf(br[5]) << 16);
      unsigned int pk3 = (unsigned)f2bf(br[6]) | ((unsigned)f2bf(br[7]) << 16);
      uint4 w; w.x = pk0; w.y = pk1; w.z = pk2; w.w = pk3;
      *(uint4*)b_dst = w;
    }
    __syncthreads();
    // issue next tile loads -> regs (in flight across compute)
    if (it + 1 < DDIM / BK) {
      const int k0 = (it + 1) * BK;
      const uint4* s = (const uint4*)(a_src + k0);
      a0 = s[0]; a1 = s[1];
      const float* bs = b_src + (size_t)k0 * HDIM;
      #pragma unroll
      for (int i = 0; i < 8; i++) br[i] = bs[(size_t)i * HDIM];
    }
    // compute current tile
    #pragma unroll
    for (int ks = 0; ks < 2; ks++) {
      const int kof = ks * 32 + lhi * 8;
      bf16x8 af[4];
      #pragma unroll
      for (int fm = 0; fm < 4; fm++)
        af[fm] = *(const bf16x8*)(As + (wm * 64 + fm * 16 + l15) * LDSS + kof);
      bf16x8 bgf = *(const bf16x8*)(Bg + (wn * 16 + l15) * LDSS + kof);
      bf16x8 buf = *(const bf16x8*)(Bu + (wn * 16 + l15) * LDSS + kof);
      #pragma unroll
      for (int fm = 0; fm < 4; fm++) {
        accg[fm] = __builtin_amdgcn_mfma_f32_16x16x32_bf16(af[fm], bgf, accg[fm], 0, 0, 0);
        accu[fm] = __builtin_amdgcn_mfma_f32_16x16x32_bf16(af[fm], buf, accu[fm], 0, 0, 0);
      }
    }
  }

  // epilogue: silu(g)*u -> bf16 Hb  (C/D map: col=lane&15, row=(lane>>4)*4+i)
  #pragma unroll
  for (int fm = 0; fm < 4; fm++) {
    #pragma unroll
    for (int i = 0; i < 4; i++) {
      const int row = wm * 64 + fm * 16 + lhi * 4 + i;
      if (row < Msub) {
        const float g = accg[fm][i];
        const float u = accu[fm][i];
        const float h = (g / (1.0f + __expf(-g))) * u;
        Hb[(size_t)(slot0 + row) * HDIM + n0 + wn * 16 + l15] = f2bf(h);
      }
    }
  }
}

// ---------------- pass 2: Y = (H @ wd) * wsel, split-K=2, scatter ----------------
__global__ __launch_bounds__(1024, 4) void gemm_down(
    const u16* __restrict__ Hb, const float* __restrict__ wd,
    const int* __restrict__ offs, const int* __restrict__ perm,
    const float* __restrict__ wsel, float* __restrict__ y) {
  __shared__ u16 As[BM * LDSS];
  __shared__ u16 Bs[64 * LDSS];

  const int e = blockIdx.y;
  const int s0 = offs[e], s1 = offs[e + 1];
  const int zz = blockIdx.z;           // bit0: M-half, bit1: K-half
  const int slot0 = s0 + (zz & 1) * BM;
  if (slot0 >= s1) return;
  const int Msub = s1 - slot0;
  const int n0 = blockIdx.x * 64;
  const int kbase = (zz >> 1) * (HDIM / 2);

  const float* Wd = wd + (size_t)e * HDIM * DDIM;

  const int t = threadIdx.x;
  const int lane = t & 63;
  const int W = t >> 6;
  const int wm = W >> 2;
  const int wn = W & 3;
  const int l15 = lane & 15;
  const int lhi = lane >> 4;

  const int a_row = t >> 2;
  const int a_ck = (t & 3) * 16;
  const u16* a_src = Hb + (size_t)min(slot0 + a_row, NTOK - 1) * HDIM + a_ck + kbase;
  u16* a_dst = As + a_row * LDSS + a_ck;

  const bool do_b = (t < 512);
  const int b_n = t & 63;
  const int b_c8 = (t >> 6) & 7;
  const float* b_src = Wd + (size_t)(kbase + b_c8 * 8) * DDIM + n0 + b_n;
  u16* b_dst = Bs + b_n * LDSS + b_c8 * 8;

  uint4 a0, a1;
  float br[8];

  f32x4 acc[4] = {{0.f,0.f,0.f,0.f},{0.f,0.f,0.f,0.f},{0.f,0.f,0.f,0.f},{0.f,0.f,0.f,0.f}};

  {
    const uint4* s = (const uint4*)(a_src + 0);
    a0 = s[0]; a1 = s[1];
    if (do_b) {
      #pragma unroll
      for (int i = 0; i < 8; i++) br[i] = b_src[(size_t)i * DDIM];
    }
  }

  const int NIT = (HDIM / 2) / BK;  // 32
  for (int it = 0; it < NIT; ++it) {
    if (it > 0) __syncthreads();
    ((uint4*)a_dst)[0] = a0;
    ((uint4*)a_dst)[1] = a1;
    if (do_b) {
      unsigned int pk0 = (unsigned)f2bf(br[0]) | ((unsigned)f2bf(br[1]) << 16);
      unsigned int pk1 = (unsigned)f2bf(br[2]) | ((unsigned)f2bf(br[3]) << 16);
      unsigned int pk2 = (unsigned)f2bf(br[4]) | ((unsigned)f2bf(br[5]) << 16);
      unsigned int pk3 = (unsigned)f2bf(br[6]) | ((unsigned)f2bf(br[7]) << 16);
      uint4 w; w.x = pk0; w.y = pk1; w.z = pk2; w.w = pk3;
      *(uint4*)b_dst = w;
    }
    __syncthreads();
    if (it + 1 < NIT) {
      const int k0 = (it + 1) * BK;
      const uint4* s = (const uint4*)(a_src + k0);
      a0 = s[0]; a1 = s[1];
      if (do_b) {
        const float* bs = b_src + (size_t)k0 * DDIM;
        #pragma unroll
        for (int i = 0; i < 8; i++) br[i] = bs[(size_t)i * DDIM];
      }
    }
    #pragma unroll
    for (int ks = 0; ks < 2; ks++) {
      const int kof = ks * 32 + lhi * 8;
      bf16x8 af[4];
      #pragma unroll
      for (int fm = 0; fm < 4; fm++)
        af[fm] = *(const bf16x8*)(As + (wm * 64 + fm * 16 + l15) * LDSS + kof);
      bf16x8 bf = *(const bf16x8*)(Bs + (wn * 16 + l15) * LDSS + kof);
      #pragma unroll
      for (int fm = 0; fm < 4; fm++)
        acc[fm] = __builtin_amdgcn_mfma_f32_16x16x32_bf16(af[fm], bf, acc[fm], 0, 0, 0);
    }
  }

  // epilogue: scale by routing weight, scatter-add (2 K-halves -> commutative, deterministic)
  #pragma unroll
  for (int fm = 0; fm < 4; fm++) {
    #pragma unroll
    for (int i = 0; i < 4; i++) {
      const int row = wm * 64 + fm * 16 + lhi * 4 + i;
      if (row < Msub) {
        const int slot = slot0 + row;
        const int tok = perm[slot];
        const float w = wsel[slot];
        atomicAdd(y + (size_t)tok * DDIM + n0 + wn * 16 + l15, acc[fm][i] * w);
      }
    }
  }
}

extern "C" void kernel_launch(void* const* d_in, const int* in_sizes, int n_in,
                              void* d_out, int out_size, void* d_ws, size_t ws_size,
                              hipStream_t stream) {
  const float* x  = (const float*)d_in[0];
  const float* cw = (const float*)d_in[1];
  const float* wg = (const float*)d_in[2];
  const float* wu = (const float*)d_in[3];
  const float* wd = (const float*)d_in[4];
  float* y = (float*)d_out;

  char* ws = (char*)d_ws;
  int* offs   = (int*)ws;                         // 16 ints
  int* perm   = (int*)(ws + 64);                  // 2048 ints
  float* wsel = (float*)(ws + 64 + NTOK * 4);     // 2048 floats
  u16* Xb = (u16*)(ws + 32768);                                    // 4 MB
  u16* Hb = (u16*)(ws + 32768 + (size_t)NTOK * DDIM * 2);          // 16 MB

  hipMemsetAsync(d_out, 0, (size_t)NTOK * DDIM * sizeof(float), stream);
  route_kernel<<<1, 256, 0, stream>>>(cw, offs, perm, wsel);
  gather_x<<<NTOK, 256, 0, stream>>>(x, perm, Xb);
  gemm_swiglu<<<dim3(HDIM / 64, KEXP, 2), 1024, 0, stream>>>(Xb, wg, wu, offs, Hb);
  gemm_down<<<dim3(DDIM / 64, KEXP, 4), 1024, 0, stream>>>(Hb, wd, offs, perm, wsel, y);
}

// Round 5
// 190.228 us; speedup vs baseline: 1.3777x; 1.2682x over previous
//
#include <hip/hip_runtime.h>

typedef __attribute__((ext_vector_type(8))) short bf16x8;
typedef __attribute__((ext_vector_type(4))) float f32x4;
typedef unsigned short u16;

#define NTOK 2048
#define DDIM 1024
#define HDIM 4096
#define KEXP 8

#define BM 320   // covers any realistic expert count in ONE tile (counts ~256±15)
#define BK 64
#define LDSS 72  // LDS row stride in bf16 elems (144B): b128 reads 2-way banks (free)
#define NDESC 16

__device__ __forceinline__ u16 f2bf(float f) {
  union { float f; unsigned int u; } c; c.f = f;
  unsigned int u = c.u;
  return (u16)((u + 0x7FFFu + ((u >> 16) & 1u)) >> 16);  // RNE
}

// ---------------- routing: counting sort + tile worklist ----------------
__global__ void route_kernel(const float* __restrict__ cw, int* __restrict__ offs,
                             int* __restrict__ perm, float* __restrict__ wsel,
                             int* __restrict__ desc) {
  __shared__ int cnt[KEXP];
  __shared__ int base[KEXP];
  const int t = threadIdx.x;  // 256 threads, 8 tokens each
  if (t < KEXP) cnt[t] = 0;
  __syncthreads();
  int eid[8]; float wv[8];
  #pragma unroll
  for (int i = 0; i < 8; i++) {
    const int tok = t * 8 + i;
    const float* p = cw + tok * KEXP;
    int best = 0; float bw = p[0];
    #pragma unroll
    for (int k = 1; k < KEXP; k++) { float v = p[k]; if (v > bw) { bw = v; best = k; } }
    eid[i] = best; wv[i] = bw;
    atomicAdd(&cnt[best], 1);
  }
  __syncthreads();
  if (t == 0) {
    int s = 0, nd = 0;
    for (int k = 0; k < KEXP; k++) {
      const int ck = cnt[k];
      base[k] = s; offs[k] = s;
      for (int m0 = 0; m0 < ck && nd < NDESC; m0 += BM)
        desc[nd++] = (k << 12) | (s + m0);   // pack expert(3b) | slot0(12b)
      s += ck;
    }
    offs[KEXP] = s;
    for (; nd < NDESC; nd++) desc[nd] = -1;
  }
  __syncthreads();
  #pragma unroll
  for (int i = 0; i < 8; i++) {
    const int tok = t * 8 + i;
    const int pos = atomicAdd(&base[eid[i]], 1);
    perm[pos] = tok;
    wsel[pos] = wv[i];
  }
}

// ---------------- gather x rows into expert-sorted bf16 ----------------
__global__ void gather_x(const float* __restrict__ x, const int* __restrict__ perm,
                         u16* __restrict__ Xb) {
  const int slot = blockIdx.x;
  const int tok = perm[slot];
  const int t = threadIdx.x;  // 256
  float4 v = ((const float4*)(x + (size_t)tok * DDIM))[t];
  ushort4 o; o.x = f2bf(v.x); o.y = f2bf(v.y); o.z = f2bf(v.z); o.w = f2bf(v.w);
  ((ushort4*)(Xb + (size_t)slot * DDIM))[t] = o;
}

// ---------------- pass 1: H = silu(X@wg) * (X@wu) ----------------
// 1024 thr = 16 waves (4m x 4n), BM=320, BN=64, BK=64.
// B1 = __syncthreads (read->write hazard; vmcnt drain ~free: loads consumed next).
// B2 = raw s_barrier + lgkmcnt(0): prefetch loads stay in flight across compute.
__global__ __launch_bounds__(1024, 4) void gemm_swiglu(
    const u16* __restrict__ Xb,
    const float* __restrict__ wg, const float* __restrict__ wu,
    const int* __restrict__ offs, const int* __restrict__ desc,
    u16* __restrict__ Hb) {
  __shared__ u16 As[BM * LDSS];
  __shared__ u16 Bg[64 * LDSS];
  __shared__ u16 Bu[64 * LDSS];

  const int d = desc[blockIdx.y];
  if (d < 0) return;
  const int e = d >> 12;
  const int slot0 = d & 0xFFF;
  const int Msub = offs[e + 1] - slot0;
  const int n0 = blockIdx.x * 64;

  const int t = threadIdx.x;
  const int lane = t & 63;
  const int W = t >> 6;      // wave 0..15
  const int wm = W >> 2;     // 4 m-strips of 80 rows
  const int wn = W & 3;      // 4 n-strips of 16 cols
  const int l15 = lane & 15;
  const int lhi = lane >> 4;

  // A staging: threads 0..639 -> row t>>1, 32 contiguous elems (4x uint4) at (t&1)*32
  const bool do_a = t < 640;
  const int a_row = t >> 1;
  const int a_ck = (t & 1) * 32;
  const u16* a_src = Xb + (size_t)min(slot0 + a_row, NTOK - 1) * DDIM + a_ck;
  u16* a_dst = As + a_row * LDSS + a_ck;

  // B staging: t<512 -> Bg, t>=512 -> Bu; 8 coalesced scalar f32 loads, one b128 write.
  const float* Wsrc = ((t < 512) ? wg : wu) + (size_t)e * DDIM * HDIM;
  const int b_n = t & 63;
  const int b_c8 = (t >> 6) & 7;
  const float* b_src = Wsrc + (size_t)(b_c8 * 8) * HDIM + n0 + b_n;
  u16* b_dst = ((t < 512) ? Bg : Bu) + b_n * LDSS + b_c8 * 8;

  uint4 a0 = {}, a1 = {}, a2 = {}, a3 = {};
  float br[8];

  f32x4 accg[5] = {};
  f32x4 accu[5] = {};

  // prologue loads for tile 0
  if (do_a) {
    const uint4* s = (const uint4*)a_src;
    a0 = s[0]; a1 = s[1]; a2 = s[2]; a3 = s[3];
  }
  #pragma unroll
  for (int i = 0; i < 8; i++) br[i] = b_src[(size_t)i * HDIM];

  #pragma unroll 1
  for (int it = 0; it < DDIM / BK; ++it) {
    if (it) __syncthreads();   // B1: LDS readers of prev tile done (full fence, race-safe)
    // write current tile regs -> LDS (32 elems per A thread: full k coverage)
    if (do_a) {
      uint4* dd = (uint4*)a_dst;
      dd[0] = a0; dd[1] = a1; dd[2] = a2; dd[3] = a3;
    }
    {
      uint4 w;
      w.x = (unsigned)f2bf(br[0]) | ((unsigned)f2bf(br[1]) << 16);
      w.y = (unsigned)f2bf(br[2]) | ((unsigned)f2bf(br[3]) << 16);
      w.z = (unsigned)f2bf(br[4]) | ((unsigned)f2bf(br[5]) << 16);
      w.w = (unsigned)f2bf(br[6]) | ((unsigned)f2bf(br[7]) << 16);
      *(uint4*)b_dst = w;
    }
    // issue next tile loads -> regs; they stay in flight across B2
    if (it + 1 < DDIM / BK) {
      const int k0 = (it + 1) * BK;
      if (do_a) {
        const uint4* s = (const uint4*)(a_src + k0);
        a0 = s[0]; a1 = s[1]; a2 = s[2]; a3 = s[3];
      }
      const float* bs = b_src + (size_t)k0 * HDIM;
      #pragma unroll
      for (int i = 0; i < 8; i++) br[i] = bs[(size_t)i * HDIM];
    }
    asm volatile("s_waitcnt lgkmcnt(0)" ::: "memory");  // own ds_writes visible
    __builtin_amdgcn_sched_barrier(0);
    __builtin_amdgcn_s_barrier();                        // B2: NO vmcnt drain
    __builtin_amdgcn_sched_barrier(0);
    // compute current tile
    #pragma unroll
    for (int ks = 0; ks < 2; ks++) {
      const int kof = ks * 32 + lhi * 8;
      bf16x8 af[5];
      #pragma unroll
      for (int fm = 0; fm < 5; fm++)
        af[fm] = *(const bf16x8*)(As + (wm * 80 + fm * 16 + l15) * LDSS + kof);
      bf16x8 bgf = *(const bf16x8*)(Bg + (wn * 16 + l15) * LDSS + kof);
      bf16x8 buf = *(const bf16x8*)(Bu + (wn * 16 + l15) * LDSS + kof);
      #pragma unroll
      for (int fm = 0; fm < 5; fm++) {
        accg[fm] = __builtin_amdgcn_mfma_f32_16x16x32_bf16(af[fm], bgf, accg[fm], 0, 0, 0);
        accu[fm] = __builtin_amdgcn_mfma_f32_16x16x32_bf16(af[fm], buf, accu[fm], 0, 0, 0);
      }
    }
  }

  // epilogue: silu(g)*u -> bf16 Hb  (C/D map: col=lane&15, row=(lane>>4)*4+i)
  #pragma unroll
  for (int fm = 0; fm < 5; fm++) {
    #pragma unroll
    for (int i = 0; i < 4; i++) {
      const int row = wm * 80 + fm * 16 + lhi * 4 + i;
      if (row < Msub) {
        const float g = accg[fm][i];
        const float u = accu[fm][i];
        const float h = (g / (1.0f + __expf(-g))) * u;
        Hb[(size_t)(slot0 + row) * HDIM + n0 + wn * 16 + l15] = f2bf(h);
      }
    }
  }
}

// ---------------- pass 2: Y = (H @ wd) * wsel, split-K=4, scatter-add ----------------
__global__ __launch_bounds__(1024, 4) void gemm_down(
    const u16* __restrict__ Hb, const float* __restrict__ wd,
    const int* __restrict__ offs, const int* __restrict__ desc,
    const int* __restrict__ perm, const float* __restrict__ wsel,
    float* __restrict__ y) {
  __shared__ u16 As[BM * LDSS];
  __shared__ u16 Bs[64 * LDSS];

  const int d = desc[blockIdx.y];
  if (d < 0) return;
  const int e = d >> 12;
  const int slot0 = d & 0xFFF;
  const int Msub = offs[e + 1] - slot0;
  const int n0 = blockIdx.x * 64;
  const int kbase = blockIdx.z * (HDIM / 4);

  const float* Wd = wd + (size_t)e * HDIM * DDIM;

  const int t = threadIdx.x;
  const int lane = t & 63;
  const int W = t >> 6;
  const int wm = W >> 2;
  const int wn = W & 3;
  const int l15 = lane & 15;
  const int lhi = lane >> 4;

  const bool do_a = t < 640;
  const int a_row = t >> 1;
  const int a_ck = (t & 1) * 32;
  const u16* a_src = Hb + (size_t)min(slot0 + a_row, NTOK - 1) * HDIM + kbase + a_ck;
  u16* a_dst = As + a_row * LDSS + a_ck;

  const bool do_b = t < 512;
  const int b_n = t & 63;
  const int b_c8 = (t >> 6) & 7;
  const float* b_src = Wd + (size_t)(kbase + b_c8 * 8) * DDIM + n0 + b_n;
  u16* b_dst = Bs + b_n * LDSS + b_c8 * 8;

  uint4 a0 = {}, a1 = {}, a2 = {}, a3 = {};
  float br[8];

  f32x4 acc[5] = {};

  if (do_a) {
    const uint4* s = (const uint4*)a_src;
    a0 = s[0]; a1 = s[1]; a2 = s[2]; a3 = s[3];
  }
  if (do_b) {
    #pragma unroll
    for (int i = 0; i < 8; i++) br[i] = b_src[(size_t)i * DDIM];
  }

  const int NIT = (HDIM / 4) / BK;  // 16
  #pragma unroll 1
  for (int it = 0; it < NIT; ++it) {
    if (it) __syncthreads();   // B1 (race-safe)
    if (do_a) {
      uint4* dd = (uint4*)a_dst;
      dd[0] = a0; dd[1] = a1; dd[2] = a2; dd[3] = a3;
    }
    if (do_b) {
      uint4 w;
      w.x = (unsigned)f2bf(br[0]) | ((unsigned)f2bf(br[1]) << 16);
      w.y = (unsigned)f2bf(br[2]) | ((unsigned)f2bf(br[3]) << 16);
      w.z = (unsigned)f2bf(br[4]) | ((unsigned)f2bf(br[5]) << 16);
      w.w = (unsigned)f2bf(br[6]) | ((unsigned)f2bf(br[7]) << 16);
      *(uint4*)b_dst = w;
    }
    if (it + 1 < NIT) {
      const int k0 = (it + 1) * BK;
      if (do_a) {
        const uint4* s = (const uint4*)(a_src + k0);
        a0 = s[0]; a1 = s[1]; a2 = s[2]; a3 = s[3];
      }
      if (do_b) {
        const float* bs = b_src + (size_t)k0 * DDIM;
        #pragma unroll
        for (int i = 0; i < 8; i++) br[i] = bs[(size_t)i * DDIM];
      }
    }
    asm volatile("s_waitcnt lgkmcnt(0)" ::: "memory");
    __builtin_amdgcn_sched_barrier(0);
    __builtin_amdgcn_s_barrier();   // B2
    __builtin_amdgcn_sched_barrier(0);
    #pragma unroll
    for (int ks = 0; ks < 2; ks++) {
      const int kof = ks * 32 + lhi * 8;
      bf16x8 af[5];
      #pragma unroll
      for (int fm = 0; fm < 5; fm++)
        af[fm] = *(const bf16x8*)(As + (wm * 80 + fm * 16 + l15) * LDSS + kof);
      bf16x8 bf = *(const bf16x8*)(Bs + (wn * 16 + l15) * LDSS + kof);
      #pragma unroll
      for (int fm = 0; fm < 5; fm++)
        acc[fm] = __builtin_amdgcn_mfma_f32_16x16x32_bf16(af[fm], bf, acc[fm], 0, 0, 0);
    }
  }

  // epilogue: scale by routing weight, scatter-add (4 K-quarters, commutative)
  #pragma unroll
  for (int fm = 0; fm < 5; fm++) {
    #pragma unroll
    for (int i = 0; i < 4; i++) {
      const int row = wm * 80 + fm * 16 + lhi * 4 + i;
      if (row < Msub) {
        const int slot = slot0 + row;
        const int tok = perm[slot];
        const float w = wsel[slot];
        atomicAdd(y + (size_t)tok * DDIM + n0 + wn * 16 + l15, acc[fm][i] * w);
      }
    }
  }
}

extern "C" void kernel_launch(void* const* d_in, const int* in_sizes, int n_in,
                              void* d_out, int out_size, void* d_ws, size_t ws_size,
                              hipStream_t stream) {
  const float* x  = (const float*)d_in[0];
  const float* cw = (const float*)d_in[1];
  const float* wg = (const float*)d_in[2];
  const float* wu = (const float*)d_in[3];
  const float* wd = (const float*)d_in[4];
  float* y = (float*)d_out;

  char* ws = (char*)d_ws;
  int* offs   = (int*)ws;                          // 16 ints
  int* desc   = (int*)(ws + 64);                   // 16 ints
  int* perm   = (int*)(ws + 128);                  // 2048 ints
  float* wsel = (float*)(ws + 128 + NTOK * 4);     // 2048 floats
  u16* Xb = (u16*)(ws + 32768);                                    // 4 MB
  u16* Hb = (u16*)(ws + 32768 + (size_t)NTOK * DDIM * 2);          // 16 MB

  hipMemsetAsync(d_out, 0, (size_t)NTOK * DDIM * sizeof(float), stream);
  route_kernel<<<1, 256, 0, stream>>>(cw, offs, perm, wsel, desc);
  gather_x<<<NTOK, 256, 0, stream>>>(x, perm, Xb);
  gemm_swiglu<<<dim3(HDIM / 64, NDESC), 1024, 0, stream>>>(Xb, wg, wu, offs, desc, Hb);
  gemm_down<<<dim3(DDIM / 64, NDESC, 4), 1024, 0, stream>>>(Hb, wd, offs, desc, perm, wsel, y);
}

// Round 6
// 163.970 us; speedup vs baseline: 1.5983x; 1.1601x over previous
//
#include <hip/hip_runtime.h>

typedef __attribute__((ext_vector_type(8))) short bf16x8;
typedef __attribute__((ext_vector_type(4))) float f32x4;
typedef unsigned short u16;

#define NTOK 2048
#define DDIM 1024
#define HDIM 4096
#define KEXP 8

#define BM 320   // covers any realistic expert count in ONE tile (counts ~256±15)
#define BN 128
#define BK 64
#define LDSS 72  // LDS row stride in bf16 elems (144B): b128 reads 2-way banks (free)
#define NDESC 16

__device__ __forceinline__ u16 f2bf(float f) {
  union { float f; unsigned int u; } c; c.f = f;
  unsigned int u = c.u;
  return (u16)((u + 0x7FFFu + ((u >> 16) & 1u)) >> 16);  // RNE
}
__device__ __forceinline__ unsigned pk2(float a, float b) {
  return (unsigned)f2bf(a) | ((unsigned)f2bf(b) << 16);
}

// ---------------- routing: counting sort + tile worklist ----------------
__global__ void route_kernel(const float* __restrict__ cw, int* __restrict__ offs,
                             int* __restrict__ perm, float* __restrict__ wsel,
                             int* __restrict__ desc) {
  __shared__ int cnt[KEXP];
  __shared__ int base[KEXP];
  const int t = threadIdx.x;  // 256 threads, 8 tokens each
  if (t < KEXP) cnt[t] = 0;
  __syncthreads();
  int eid[8]; float wv[8];
  #pragma unroll
  for (int i = 0; i < 8; i++) {
    const int tok = t * 8 + i;
    const float* p = cw + tok * KEXP;
    int best = 0; float bw = p[0];
    #pragma unroll
    for (int k = 1; k < KEXP; k++) { float v = p[k]; if (v > bw) { bw = v; best = k; } }
    eid[i] = best; wv[i] = bw;
    atomicAdd(&cnt[best], 1);
  }
  __syncthreads();
  if (t == 0) {
    int s = 0, nd = 0;
    for (int k = 0; k < KEXP; k++) {
      const int ck = cnt[k];
      base[k] = s; offs[k] = s;
      for (int m0 = 0; m0 < ck && nd < NDESC; m0 += BM)
        desc[nd++] = (k << 12) | (s + m0);   // pack expert(3b) | slot0(12b)
      s += ck;
    }
    offs[KEXP] = s;
    for (; nd < NDESC; nd++) desc[nd] = -1;
  }
  __syncthreads();
  #pragma unroll
  for (int i = 0; i < 8; i++) {
    const int tok = t * 8 + i;
    const int pos = atomicAdd(&base[eid[i]], 1);
    perm[pos] = tok;
    wsel[pos] = wv[i];
  }
}

// ---------------- gather x rows into expert-sorted bf16 ----------------
__global__ void gather_x(const float* __restrict__ x, const int* __restrict__ perm,
                         u16* __restrict__ Xb) {
  const int slot = blockIdx.x;
  const int tok = perm[slot];
  const int t = threadIdx.x;  // 256
  float4 v = ((const float4*)(x + (size_t)tok * DDIM))[t];
  ushort4 o; o.x = f2bf(v.x); o.y = f2bf(v.y); o.z = f2bf(v.z); o.w = f2bf(v.w);
  ((ushort4*)(Xb + (size_t)slot * DDIM))[t] = o;
}

// ---------------- pass 1: H = silu(X@wg) * (X@wu) ----------------
// 1024 thr = 16 waves (4m x 4n), BM=320, BN=128, BK=64. Wave tile 80x32.
// A (L2-resident Xb): synchronous stage. B (HBM weights): reg-prefetch
// spanning B2 (raw s_barrier + lgkmcnt(0), no vmcnt drain).
__global__ __launch_bounds__(1024, 4) void gemm_swiglu(
    const u16* __restrict__ Xb,
    const float* __restrict__ wg, const float* __restrict__ wu,
    const int* __restrict__ offs, const int* __restrict__ desc,
    u16* __restrict__ Hb) {
  __shared__ u16 As[BM * LDSS];
  __shared__ u16 Bg[BN * LDSS];
  __shared__ u16 Bu[BN * LDSS];

  const int d = desc[blockIdx.y];
  if (d < 0) return;
  const int e = d >> 12;
  const int slot0 = d & 0xFFF;
  const int Msub = offs[e + 1] - slot0;
  const int n0 = blockIdx.x * BN;

  const int t = threadIdx.x;
  const int lane = t & 63;
  const int W = t >> 6;      // wave 0..15
  const int wm = W >> 2;     // 4 m-strips of 80 rows
  const int wn = W & 3;      // 4 n-strips of 32 cols
  const int l15 = lane & 15;
  const int lhi = lane >> 4;

  // A staging (sync): threads 0..639 -> row t>>1, 32 elems (4x uint4) at (t&1)*32
  const bool do_a = t < 640;
  const int a_row = t >> 1;
  const int a_ck = (t & 1) * 32;
  const u16* a_src = Xb + (size_t)min(slot0 + a_row, NTOK - 1) * DDIM + a_ck;
  u16* a_dst = As + a_row * LDSS + a_ck;

  // B staging (prefetch): tb=t&511 within matrix (t<512 -> Bg, else Bu).
  // thread -> n-pair n2=(tb&63)*2, k-chunk kk=(tb>>6)*8: 8 float2 loads.
  const int tb = t & 511;
  const float* Wsrc = ((t < 512) ? wg : wu) + (size_t)e * DDIM * HDIM;
  const int b_n2 = (tb & 63) * 2;
  const int b_kk = (tb >> 6) * 8;
  const float* b_src = Wsrc + (size_t)b_kk * HDIM + n0 + b_n2;
  u16* b_dst = ((t < 512) ? Bg : Bu) + b_n2 * LDSS + b_kk;

  float2 br[8];
  f32x4 accg[5][2] = {};
  f32x4 accu[5][2] = {};

  // prologue: issue B tile-0 loads
  #pragma unroll
  for (int i = 0; i < 8; i++) br[i] = *(const float2*)(b_src + (size_t)i * HDIM);

  #pragma unroll 1
  for (int it = 0; it < DDIM / BK; ++it) {
    const int k0 = it * BK;
    if (it) __syncthreads();   // B1: full fence (readers of prev tile done)
    // A: sync load + write (L2-resident, short stall)
    if (do_a) {
      const uint4* s = (const uint4*)(a_src + k0);
      uint4 s0 = s[0], s1 = s[1], s2 = s[2], s3 = s[3];
      uint4* dd = (uint4*)a_dst;
      dd[0] = s0; dd[1] = s1; dd[2] = s2; dd[3] = s3;
    }
    // B: write current tile from prefetched regs (rows n2, n2+1)
    {
      uint4 w0, w1;
      w0.x = pk2(br[0].x, br[1].x); w0.y = pk2(br[2].x, br[3].x);
      w0.z = pk2(br[4].x, br[5].x); w0.w = pk2(br[6].x, br[7].x);
      w1.x = pk2(br[0].y, br[1].y); w1.y = pk2(br[2].y, br[3].y);
      w1.z = pk2(br[4].y, br[5].y); w1.w = pk2(br[6].y, br[7].y);
      *(uint4*)b_dst = w0;
      *(uint4*)(b_dst + LDSS) = w1;
    }
    // issue next-tile B loads; they stay in flight across B2
    if (it + 1 < DDIM / BK) {
      const float* bs = b_src + (size_t)(k0 + BK) * HDIM;
      #pragma unroll
      for (int i = 0; i < 8; i++) br[i] = *(const float2*)(bs + (size_t)i * HDIM);
    }
    asm volatile("s_waitcnt lgkmcnt(0)" ::: "memory");  // own ds_writes visible
    __builtin_amdgcn_sched_barrier(0);
    __builtin_amdgcn_s_barrier();                        // B2: NO vmcnt drain
    __builtin_amdgcn_sched_barrier(0);
    // compute current tile
    #pragma unroll
    for (int ks = 0; ks < 2; ks++) {
      const int kof = ks * 32 + lhi * 8;
      bf16x8 bgf[2], buf[2];
      #pragma unroll
      for (int fn = 0; fn < 2; fn++) {
        bgf[fn] = *(const bf16x8*)(Bg + (wn * 32 + fn * 16 + l15) * LDSS + kof);
        buf[fn] = *(const bf16x8*)(Bu + (wn * 32 + fn * 16 + l15) * LDSS + kof);
      }
      #pragma unroll
      for (int fm = 0; fm < 5; fm++) {
        bf16x8 af = *(const bf16x8*)(As + (wm * 80 + fm * 16 + l15) * LDSS + kof);
        #pragma unroll
        for (int fn = 0; fn < 2; fn++) {
          accg[fm][fn] = __builtin_amdgcn_mfma_f32_16x16x32_bf16(af, bgf[fn], accg[fm][fn], 0, 0, 0);
          accu[fm][fn] = __builtin_amdgcn_mfma_f32_16x16x32_bf16(af, buf[fn], accu[fm][fn], 0, 0, 0);
        }
      }
    }
  }

  // epilogue: silu(g)*u -> bf16 Hb  (C/D map: col=lane&15, row=(lane>>4)*4+i)
  #pragma unroll
  for (int fm = 0; fm < 5; fm++) {
    #pragma unroll
    for (int i = 0; i < 4; i++) {
      const int row = wm * 80 + fm * 16 + lhi * 4 + i;
      if (row < Msub) {
        const size_t base = (size_t)(slot0 + row) * HDIM + n0 + wn * 32;
        #pragma unroll
        for (int fn = 0; fn < 2; fn++) {
          const float g = accg[fm][fn][i];
          const float u = accu[fm][fn][i];
          const float h = (g / (1.0f + __expf(-g))) * u;
          Hb[base + fn * 16 + l15] = f2bf(h);
        }
      }
    }
  }
}

// ---------------- pass 2: Y = (H @ wd) * wsel, split-K=4, scatter-add ----------------
__global__ __launch_bounds__(1024, 4) void gemm_down(
    const u16* __restrict__ Hb, const float* __restrict__ wd,
    const int* __restrict__ offs, const int* __restrict__ desc,
    const int* __restrict__ perm, const float* __restrict__ wsel,
    float* __restrict__ y) {
  __shared__ u16 As[BM * LDSS];
  __shared__ u16 Bs[BN * LDSS];

  const int d = desc[blockIdx.y];
  if (d < 0) return;
  const int e = d >> 12;
  const int slot0 = d & 0xFFF;
  const int Msub = offs[e + 1] - slot0;
  const int n0 = blockIdx.x * BN;           // DDIM/128 = 8 n-blocks
  const int kbase = blockIdx.z * (HDIM / 4);

  const float* Wd = wd + (size_t)e * HDIM * DDIM;

  const int t = threadIdx.x;
  const int lane = t & 63;
  const int W = t >> 6;
  const int wm = W >> 2;
  const int wn = W & 3;
  const int l15 = lane & 15;
  const int lhi = lane >> 4;

  const bool do_a = t < 640;
  const int a_row = t >> 1;
  const int a_ck = (t & 1) * 32;
  const u16* a_src = Hb + (size_t)min(slot0 + a_row, NTOK - 1) * HDIM + kbase + a_ck;
  u16* a_dst = As + a_row * LDSS + a_ck;

  // B staging: all 1024 threads, one matrix: n-pair n2=(t&63)*2, kk=(t>>6)*4.
  const int b_n2 = (t & 63) * 2;
  const int b_kk = (t >> 6) * 4;
  const float* b_src = Wd + (size_t)(kbase + b_kk) * DDIM + n0 + b_n2;
  u16* b_dst = Bs + b_n2 * LDSS + b_kk;

  float2 br[4];
  f32x4 acc[5][2] = {};

  #pragma unroll
  for (int i = 0; i < 4; i++) br[i] = *(const float2*)(b_src + (size_t)i * DDIM);

  const int NIT = (HDIM / 4) / BK;  // 16
  #pragma unroll 1
  for (int it = 0; it < NIT; ++it) {
    const int k0 = it * BK;
    if (it) __syncthreads();   // B1
    if (do_a) {
      const uint4* s = (const uint4*)(a_src + k0);
      uint4 s0 = s[0], s1 = s[1], s2 = s[2], s3 = s[3];
      uint4* dd = (uint4*)a_dst;
      dd[0] = s0; dd[1] = s1; dd[2] = s2; dd[3] = s3;
    }
    {
      uint2 w0, w1;
      w0.x = pk2(br[0].x, br[1].x); w0.y = pk2(br[2].x, br[3].x);
      w1.x = pk2(br[0].y, br[1].y); w1.y = pk2(br[2].y, br[3].y);
      *(uint2*)b_dst = w0;
      *(uint2*)(b_dst + LDSS) = w1;
    }
    if (it + 1 < NIT) {
      const float* bs = b_src + (size_t)(k0 + BK) * DDIM;
      #pragma unroll
      for (int i = 0; i < 4; i++) br[i] = *(const float2*)(bs + (size_t)i * DDIM);
    }
    asm volatile("s_waitcnt lgkmcnt(0)" ::: "memory");
    __builtin_amdgcn_sched_barrier(0);
    __builtin_amdgcn_s_barrier();   // B2
    __builtin_amdgcn_sched_barrier(0);
    #pragma unroll
    for (int ks = 0; ks < 2; ks++) {
      const int kof = ks * 32 + lhi * 8;
      bf16x8 bf[2];
      #pragma unroll
      for (int fn = 0; fn < 2; fn++)
        bf[fn] = *(const bf16x8*)(Bs + (wn * 32 + fn * 16 + l15) * LDSS + kof);
      #pragma unroll
      for (int fm = 0; fm < 5; fm++) {
        bf16x8 af = *(const bf16x8*)(As + (wm * 80 + fm * 16 + l15) * LDSS + kof);
        #pragma unroll
        for (int fn = 0; fn < 2; fn++)
          acc[fm][fn] = __builtin_amdgcn_mfma_f32_16x16x32_bf16(af, bf[fn], acc[fm][fn], 0, 0, 0);
      }
    }
  }

  // epilogue: scale by routing weight, scatter-add (4 K-quarters, commutative)
  #pragma unroll
  for (int fm = 0; fm < 5; fm++) {
    #pragma unroll
    for (int i = 0; i < 4; i++) {
      const int row = wm * 80 + fm * 16 + lhi * 4 + i;
      if (row < Msub) {
        const int slot = slot0 + row;
        const int tok = perm[slot];
        const float w = wsel[slot];
        const size_t base = (size_t)tok * DDIM + n0 + wn * 32;
        #pragma unroll
        for (int fn = 0; fn < 2; fn++)
          atomicAdd(y + base + fn * 16 + l15, acc[fm][fn][i] * w);
      }
    }
  }
}

extern "C" void kernel_launch(void* const* d_in, const int* in_sizes, int n_in,
                              void* d_out, int out_size, void* d_ws, size_t ws_size,
                              hipStream_t stream) {
  const float* x  = (const float*)d_in[0];
  const float* cw = (const float*)d_in[1];
  const float* wg = (const float*)d_in[2];
  const float* wu = (const float*)d_in[3];
  const float* wd = (const float*)d_in[4];
  float* y = (float*)d_out;

  char* ws = (char*)d_ws;
  int* offs   = (int*)ws;                          // 16 ints
  int* desc   = (int*)(ws + 64);                   // 16 ints
  int* perm   = (int*)(ws + 128);                  // 2048 ints
  float* wsel = (float*)(ws + 128 + NTOK * 4);     // 2048 floats
  u16* Xb = (u16*)(ws + 32768);                                    // 4 MB
  u16* Hb = (u16*)(ws + 32768 + (size_t)NTOK * DDIM * 2);          // 16 MB

  hipMemsetAsync(d_out, 0, (size_t)NTOK * DDIM * sizeof(float), stream);
  route_kernel<<<1, 256, 0, stream>>>(cw, offs, perm, wsel, desc);
  gather_x<<<NTOK, 256, 0, stream>>>(x, perm, Xb);
  gemm_swiglu<<<dim3(HDIM / BN, NDESC), 1024, 0, stream>>>(Xb, wg, wu, offs, desc, Hb);
  gemm_down<<<dim3(DDIM / BN, NDESC, 4), 1024, 0, stream>>>(Hb, wd, offs, desc, perm, wsel, y);
}